// Round 4
// baseline (152.186 us; speedup 1.0000x reference)
//
#include <hip/hip_runtime.h>

#define CC    32
#define HH    80
#define WW    80
#define HW    6400     // 80*80
#define HPQ   77
#define WPQ   77
#define PP    5929     // 77*77
#define DD    512      // 32*4*4
#define MSTR  81
#define NTILE 93       // ceil(PP/64)
#define NCHUNK 16      // 512 / 32
#define NEGINF (-1e9f)

// ---------------- flags: invn, excl, valid, compacted valid list ----------------
__global__ __launch_bounds__(256) void k_flags(const float* __restrict__ low,
                                               const int* __restrict__ mask,
                                               float* __restrict__ invn,
                                               int* __restrict__ excl,
                                               int* __restrict__ valid,
                                               int* __restrict__ qlist,
                                               int* __restrict__ nvalid) {
    __shared__ float part[4][64];
    const int tid = threadIdx.x;
    const int pl = tid & 63;
    const int sl = tid >> 6;           // channel slice 0..3
    const int p = blockIdx.x * 64 + pl;

    float s = 0.f;
    if (p < PP) {
        int pi = p / WPQ, pj = p % WPQ;
        int base = pi * WW + pj;
        for (int c = sl * 8; c < sl * 8 + 8; ++c) {
            int b2 = c * HW + base;
#pragma unroll
            for (int di = 0; di < 4; ++di)
#pragma unroll
                for (int dj = 0; dj < 4; ++dj) {
                    float v = low[b2 + di * WW + dj];
                    s += v * v;
                }
        }
    }
    part[sl][pl] = s;
    __syncthreads();
    if (tid < 64 && p < PP) {
        float t = part[0][tid] + part[1][tid] + part[2][tid] + part[3][tid];
        invn[p] = 1.0f / (sqrtf(t) + 1e-6f);
        int pi = p / WPQ, pj = p % WPQ;
        int m00 = mask[pi * MSTR + pj];
        int m01 = mask[pi * MSTR + pj + 4];
        int m10 = mask[(pi + 4) * MSTR + pj];
        int m11 = mask[(pi + 4) * MSTR + pj + 4];
        excl[p] = (m00 == 1) ? 1 : 0;
        int v = (m00 != 0 && m01 != 0 && m10 != 0 && m11 != 0) ? 1 : 0;
        valid[p] = v;
        if (v) {
            int slot = atomicAdd(nvalid, 1);
            qlist[slot] = p;
        }
    }
}

// ---------------- score: 32 valid queries x 64 candidates per block ----------------
// K-loop: 16 chunks of 32 dk, register double-buffered staging, 1 barrier/chunk.
__global__ __launch_bounds__(256) void k_score(const float* __restrict__ low,
                                               const float* __restrict__ high,
                                               const float* __restrict__ invn,
                                               const int* __restrict__ excl,
                                               const int* __restrict__ qlist,
                                               const int* __restrict__ nvalid,
                                               float* __restrict__ pscore,
                                               int* __restrict__ pidx) {
    const int nv = *nvalid;
    const int qy = blockIdx.y;
    if (qy * 32 >= nv) return;
    const int tile = blockIdx.x;
    const int pbase = tile * 64;
    const int tid = threadIdx.x;
    const int l31 = tid & 31;
    const int qg  = tid >> 5;          // 0..7

    __shared__ float As[2][32][36];    // [buf][dk][q_local]
    __shared__ float Bs[2][32][64];    // [buf][dk][p_local]
    __shared__ float RS[32][32];
    __shared__ int   RI[32][32];

    // A staging: this thread stages query slot ql=l31, dk = qg + 8k (k<4)
    int slotA = qy * 32 + l31;
    int qA = (slotA < nv) ? qlist[slotA] : 0;
    int qi = qA / WPQ, qj = qA % WPQ;
    int offA[4];
#pragma unroll
    for (int k = 0; k < 4; ++k) {
        int dk = qg + 8 * k;
        int d16 = dk & 15;
        int di = (d16 >> 2) & 3, dj = d16 & 3;
        offA[k] = (dk >> 4) * HW + (qi + di) * WW + (qj + dj);
    }

    // B staging: p_local = tid&63, dk = tb + 4k (k<8)
    const int pl = tid & 63;
    const int tb = tid >> 6;           // 0..3
    const int pB = pbase + pl;
    const bool pok = (pB < PP);
    int ppi = pok ? pB / WPQ : 0, ppj = pok ? pB % WPQ : 0;
    int pbB = ppi * WW + ppj;
    int offB[8];
#pragma unroll
    for (int k = 0; k < 8; ++k) {
        int dk = tb + 4 * k;
        int d16 = dk & 15;
        int di = (d16 >> 2) & 3, dj = d16 & 3;
        offB[k] = (dk >> 4) * HW + pbB + di * WW + dj;
    }

    float aR[4], bR[8];
#pragma unroll
    for (int k = 0; k < 4; ++k) aR[k] = high[offA[k]];
#pragma unroll
    for (int k = 0; k < 8; ++k) bR[k] = pok ? low[offB[k]] : 0.f;

    float acc[4][2];
#pragma unroll
    for (int a = 0; a < 4; ++a) { acc[a][0] = 0.f; acc[a][1] = 0.f; }

    for (int ch = 0; ch < NCHUNK; ++ch) {
        const int buf = ch & 1;
#pragma unroll
        for (int k = 0; k < 4; ++k) As[buf][qg + 8 * k][l31] = aR[k];
#pragma unroll
        for (int k = 0; k < 8; ++k) Bs[buf][tb + 4 * k][pl] = bR[k];
        __syncthreads();
        if (ch + 1 < NCHUNK) {
#pragma unroll
            for (int k = 0; k < 4; ++k) { offA[k] += 2 * HW; aR[k] = high[offA[k]]; }
#pragma unroll
            for (int k = 0; k < 8; ++k) { offB[k] += 2 * HW; bR[k] = pok ? low[offB[k]] : 0.f; }
        }
#pragma unroll
        for (int dk = 0; dk < 32; ++dk) {
            float4 a = *reinterpret_cast<const float4*>(&As[buf][dk][qg * 4]);
            float2 b = *reinterpret_cast<const float2*>(&Bs[buf][dk][l31 * 2]);
            acc[0][0] += a.x * b.x; acc[0][1] += a.x * b.y;
            acc[1][0] += a.y * b.x; acc[1][1] += a.y * b.y;
            acc[2][0] += a.z * b.x; acc[2][1] += a.z * b.y;
            acc[3][0] += a.w * b.x; acc[3][1] += a.w * b.y;
        }
    }

    // per-thread argmax over its 2 consecutive candidates
    float best_s[4];
    int   best_i[4];
#pragma unroll
    for (int qq = 0; qq < 4; ++qq) { best_s[qq] = -3.4e38f; best_i[qq] = 0x7fffffff; }
#pragma unroll
    for (int pp = 0; pp < 2; ++pp) {
        int gp = pbase + l31 * 2 + pp;
        if (gp < PP) {
            float scale = invn[gp];
            int ex = excl[gp];
#pragma unroll
            for (int qq = 0; qq < 4; ++qq) {
                float s = ex ? NEGINF : acc[qq][pp] * scale;
                if (s > best_s[qq]) { best_s[qq] = s; best_i[qq] = gp; }
            }
        }
    }

    __syncthreads();
#pragma unroll
    for (int qq = 0; qq < 4; ++qq) {
        RS[qg * 4 + qq][l31] = best_s[qq];
        RI[qg * 4 + qq][l31] = best_i[qq];
    }
    __syncthreads();
    if (tid < 32) {
        float bs = RS[tid][0];
        int bi = RI[tid][0];
        for (int t = 1; t < 32; ++t) {     // ascending l31 = ascending idx
            float s = RS[tid][t]; int i = RI[tid][t];
            if (s > bs) { bs = s; bi = i; }
        }
        int slot = qy * 32 + tid;
        pscore[slot * NTILE + tile] = bs;
        pidx[slot * NTILE + tile] = bi;
    }
}

// ---------------- reduce partials -> best[q]: one block (64 thr) per slot ----------------
__global__ __launch_bounds__(64) void k_reduce(const float* __restrict__ pscore,
                                               const int* __restrict__ pidx,
                                               const int* __restrict__ qlist,
                                               const int* __restrict__ nvalid,
                                               int* __restrict__ best) {
    const int slot = blockIdx.x;
    if (slot >= *nvalid) return;
    const int t = threadIdx.x;
    float bs = -3.4e38f;
    int bi = 0x7fffffff;
    for (int k = t; k < NTILE; k += 64) {
        float s = pscore[slot * NTILE + k];
        int i = pidx[slot * NTILE + k];
        if (s > bs || (s == bs && i < bi)) { bs = s; bi = i; }
    }
#pragma unroll
    for (int off = 32; off >= 1; off >>= 1) {
        float s2 = __shfl_down(bs, off);
        int   i2 = __shfl_down(bi, off);
        if (s2 > bs || (s2 == bs && i2 < bi)) { bs = s2; bi = i2; }
    }
    if (t == 0) best[qlist[slot]] = bi;
}

// ---------------- prep: per-pixel count + source-offset list (c-independent) ----------------
__global__ __launch_bounds__(256) void k_prep(const int* __restrict__ best,
                                              const int* __restrict__ valid,
                                              int* __restrict__ cnt,
                                              int* __restrict__ offlist) {
    int pix = blockIdx.x * 256 + threadIdx.x;
    if (pix >= HW) return;
    int i = pix / WW, j = pix % WW;
    int n = 0;
#pragma unroll
    for (int di = 0; di < 4; ++di) {
        int qi = i - di;
        if (qi < 0 || qi >= HPQ) continue;
#pragma unroll
        for (int dj = 0; dj < 4; ++dj) {
            int qj = j - dj;
            if (qj < 0 || qj >= WPQ) continue;
            int q = qi * WPQ + qj;
            if (valid[q]) {
                int b = best[q];
                int bi = b / WPQ, bj = b % WPQ;
                offlist[pix * 16 + n] = (bi + di) * WW + (bj + dj);
                n++;
            }
        }
    }
    cnt[pix] = n;
}

// ---------------- gather + overlap-add + normalize ----------------
__global__ __launch_bounds__(256) void k_out(const float* __restrict__ low,
                                             const int* __restrict__ cnt,
                                             const int* __restrict__ offlist,
                                             float* __restrict__ out) {
    int idx = blockIdx.x * 256 + threadIdx.x;
    if (idx >= CC * HW) return;
    int c = idx / HW;
    int pix = idx % HW;
    int n = cnt[pix];
    if (n > 0) {
        int base = c * HW;
        float acc = 0.f;
        for (int t = 0; t < n; ++t)
            acc += low[base + offlist[pix * 16 + t]];
        out[idx] = acc / ((float)n + 1e-6f);
    } else {
        out[idx] = low[idx];
    }
}

extern "C" void kernel_launch(void* const* d_in, const int* in_sizes, int n_in,
                              void* d_out, int out_size, void* d_ws, size_t ws_size,
                              hipStream_t stream) {
    const float* low  = (const float*)d_in[0];
    const float* high = (const float*)d_in[1];
    const int*   mask = (const int*)d_in[2];
    float* out = (float*)d_out;

    char* ws = (char*)d_ws;
    int*   nvalid = (int*)(ws);                        // 64 B
    int*   qlist  = (int*)(ws + 64);
    float* invn   = (float*)(ws + 24064);
    int*   excl   = (int*)(ws + 48128);
    int*   valid  = (int*)(ws + 72192);
    int*   best   = (int*)(ws + 96256);
    float* pscore = (float*)(ws + 120320);             // 5952*93*4 = 2,214,144
    int*   pidx   = (int*)(ws + 2334464);              // 2,214,144
    int*   cnt    = (int*)(ws + 4548608);              // 25,600
    int*   offlist= (int*)(ws + 4574208);              // 409,600 -> end ~4.98 MB

    hipMemsetAsync(nvalid, 0, 4, stream);
    hipLaunchKernelGGL(k_flags, dim3((PP + 63) / 64), dim3(256), 0, stream,
                       low, mask, invn, excl, valid, qlist, nvalid);
    hipLaunchKernelGGL(k_score, dim3(NTILE, 186), dim3(256), 0, stream,
                       low, high, invn, excl, qlist, nvalid, pscore, pidx);
    hipLaunchKernelGGL(k_reduce, dim3(5952), dim3(64), 0, stream,
                       pscore, pidx, qlist, nvalid, best);
    hipLaunchKernelGGL(k_prep, dim3((HW + 255) / 256), dim3(256), 0, stream,
                       best, valid, cnt, offlist);
    hipLaunchKernelGGL(k_out, dim3((CC * HW + 255) / 256), dim3(256), 0, stream,
                       low, cnt, offlist, out);
}

// Round 5
// 110.536 us; speedup vs baseline: 1.3768x; 1.3768x over previous
//
#include <hip/hip_runtime.h>
#include <hip/hip_bf16.h>

#define CC    32
#define HH    80
#define WW    80
#define HW    6400     // 80*80
#define HPQ   77
#define WPQ   77
#define PP    5929     // 77*77
#define DD    512      // 32*4*4
#define MSTR  81
#define NTILE 93       // ceil(PP/64) candidate blocks of 64
#define QTILES 372     // 5952/16 worst-case query tiles
#define NEGINF (-1e9f)

typedef __attribute__((ext_vector_type(4))) float f32x4;
typedef __attribute__((ext_vector_type(8))) short bf16x8;
typedef __attribute__((ext_vector_type(8))) unsigned short u16x8;

__device__ __forceinline__ void split_bf16(float v, unsigned short& hi, unsigned short& lo) {
    __hip_bfloat16 h = __float2bfloat16(v);
    float hf = __bfloat162float(h);
    __hip_bfloat16 lw = __float2bfloat16(v - hf);
    hi = *reinterpret_cast<unsigned short*>(&h);
    lo = *reinterpret_cast<unsigned short*>(&lw);
}

// ---------------- flags: invn, excl, valid, compacted valid list ----------------
__global__ __launch_bounds__(256) void k_flags(const float* __restrict__ low,
                                               const int* __restrict__ mask,
                                               float* __restrict__ invn,
                                               int* __restrict__ excl,
                                               int* __restrict__ valid,
                                               int* __restrict__ qlist,
                                               int* __restrict__ nvalid) {
    __shared__ float part[4][64];
    const int tid = threadIdx.x;
    const int pl = tid & 63;
    const int sl = tid >> 6;           // channel slice 0..3
    const int p = blockIdx.x * 64 + pl;

    float s = 0.f;
    if (p < PP) {
        int pi = p / WPQ, pj = p % WPQ;
        int base = pi * WW + pj;
        for (int c = sl * 8; c < sl * 8 + 8; ++c) {
            int b2 = c * HW + base;
#pragma unroll
            for (int di = 0; di < 4; ++di)
#pragma unroll
                for (int dj = 0; dj < 4; ++dj) {
                    float v = low[b2 + di * WW + dj];
                    s += v * v;
                }
        }
    }
    part[sl][pl] = s;
    __syncthreads();
    if (tid < 64 && p < PP) {
        float t = part[0][tid] + part[1][tid] + part[2][tid] + part[3][tid];
        invn[p] = 1.0f / (sqrtf(t) + 1e-6f);
        int pi = p / WPQ, pj = p % WPQ;
        int m00 = mask[pi * MSTR + pj];
        int m01 = mask[pi * MSTR + pj + 4];
        int m10 = mask[(pi + 4) * MSTR + pj];
        int m11 = mask[(pi + 4) * MSTR + pj + 4];
        excl[p] = (m00 == 1) ? 1 : 0;
        int v = (m00 != 0 && m01 != 0 && m10 != 0 && m11 != 0) ? 1 : 0;
        valid[p] = v;
        if (v) {
            int slot = atomicAdd(nvalid, 1);
            qlist[slot] = p;
        }
    }
}

// ---------------- pack B: low * invn -> bf16 hi/lo in MFMA frag order ----------------
// layout: [ptile u][kstep s][lane l][j 0..7]; lane: n=l&15 (candidate), k=s*32+(l>>4)*8+j
__global__ __launch_bounds__(256) void k_packB(const float* __restrict__ low,
                                               const float* __restrict__ invn,
                                               unsigned short* __restrict__ Bhi,
                                               unsigned short* __restrict__ Blo) {
    int t = blockIdx.x * 256 + threadIdx.x;       // 372*16*64 = 380928 threads
    if (t >= QTILES * 16 * 64) return;
    int l = t & 63;
    int s = (t >> 6) & 15;
    int u = t >> 10;
    int n = l & 15, quad = l >> 4;
    int p = u * 16 + n;
    int kbase = s * 32 + quad * 8;

    u16x8 vh, vl;
    if (p < PP) {
        float sc = invn[p];
        int pi = p / WPQ, pj = p % WPQ;
        int base = (kbase >> 4) * HW + pi * WW + pj;   // c fixed across j (kbase%8==0)
#pragma unroll
        for (int j = 0; j < 8; ++j) {
            int kk = kbase + j;
            int di = (kk >> 2) & 3, dj = kk & 3;
            float v = low[base + di * WW + dj] * sc;
            unsigned short h, lo;
            split_bf16(v, h, lo);
            vh[j] = h; vl[j] = lo;
        }
    } else {
#pragma unroll
        for (int j = 0; j < 8; ++j) { vh[j] = 0; vl[j] = 0; }
    }
    int off = t * 8;
    *reinterpret_cast<u16x8*>(Bhi + off) = vh;
    *reinterpret_cast<u16x8*>(Blo + off) = vl;
}

// ---------------- pack A: high (valid queries, compacted) -> bf16 hi/lo frags ----------------
__global__ __launch_bounds__(256) void k_packA(const float* __restrict__ high,
                                               const int* __restrict__ qlist,
                                               const int* __restrict__ nvalid,
                                               unsigned short* __restrict__ Ahi,
                                               unsigned short* __restrict__ Alo) {
    int t = blockIdx.x * 256 + threadIdx.x;
    if (t >= QTILES * 16 * 64) return;
    int nv = *nvalid;
    int l = t & 63;
    int s = (t >> 6) & 15;
    int u = t >> 10;
    if ((u >> 2) * 64 >= nv) return;              // qblk inactive -> frags never read
    int m = l & 15, quad = l >> 4;
    int slot = u * 16 + m;
    int kbase = s * 32 + quad * 8;

    u16x8 vh, vl;
    if (slot < nv) {
        int q = qlist[slot];
        int qi = q / WPQ, qj = q % WPQ;
        int base = (kbase >> 4) * HW + qi * WW + qj;
#pragma unroll
        for (int j = 0; j < 8; ++j) {
            int kk = kbase + j;
            int di = (kk >> 2) & 3, dj = kk & 3;
            float v = high[base + di * WW + dj];
            unsigned short h, lo;
            split_bf16(v, h, lo);
            vh[j] = h; vl[j] = lo;
        }
    } else {
#pragma unroll
        for (int j = 0; j < 8; ++j) { vh[j] = 0; vl[j] = 0; }
    }
    int off = t * 8;
    *reinterpret_cast<u16x8*>(Ahi + off) = vh;
    *reinterpret_cast<u16x8*>(Alo + off) = vl;
}

// ---------------- score: MFMA bf16-split GEMM + argmax ----------------
// grid (93 pblk, 93 qblk), 256 thr = 4 waves; wave w: qtile qblk*4+w x 64 candidates.
__global__ __launch_bounds__(256) void k_score(const unsigned short* __restrict__ Ahi,
                                               const unsigned short* __restrict__ Alo,
                                               const unsigned short* __restrict__ Bhi,
                                               const unsigned short* __restrict__ Blo,
                                               const int* __restrict__ excl,
                                               const int* __restrict__ nvalid,
                                               float* __restrict__ pscore,
                                               int* __restrict__ pidx) {
    const int nv = *nvalid;
    const int qblk = blockIdx.y;
    if (qblk * 64 >= nv) return;
    const int pblk = blockIdx.x;
    const int w = threadIdx.x >> 6;
    const int l = threadIdx.x & 63;
    const int qtile = qblk * 4 + w;

    f32x4 acc[4];
#pragma unroll
    for (int pt = 0; pt < 4; ++pt) acc[pt] = (f32x4){0.f, 0.f, 0.f, 0.f};

    const int abase = qtile * 8192 + l * 8;       // [tile][s][lane][8]
    const int bbase0 = pblk * 4 * 8192 + l * 8;   // ptile = pblk*4+pt

#pragma unroll 4
    for (int s = 0; s < 16; ++s) {
        bf16x8 ah = *reinterpret_cast<const bf16x8*>(Ahi + abase + s * 512);
        bf16x8 al = *reinterpret_cast<const bf16x8*>(Alo + abase + s * 512);
#pragma unroll
        for (int pt = 0; pt < 4; ++pt) {
            int boff = bbase0 + pt * 8192 + s * 512;
            bf16x8 bh = *reinterpret_cast<const bf16x8*>(Bhi + boff);
            bf16x8 bl = *reinterpret_cast<const bf16x8*>(Blo + boff);
            acc[pt] = __builtin_amdgcn_mfma_f32_16x16x32_bf16(ah, bh, acc[pt], 0, 0, 0);
            acc[pt] = __builtin_amdgcn_mfma_f32_16x16x32_bf16(ah, bl, acc[pt], 0, 0, 0);
            acc[pt] = __builtin_amdgcn_mfma_f32_16x16x32_bf16(al, bh, acc[pt], 0, 0, 0);
        }
    }

    // C/D layout: col n = l&15 (candidate), row m = (l>>4)*4 + reg (query)
    const int n = l & 15, quad = l >> 4;
    float bs[4]; int bi[4];
#pragma unroll
    for (int r = 0; r < 4; ++r) { bs[r] = -3.4e38f; bi[r] = 0x7fffffff; }
#pragma unroll
    for (int pt = 0; pt < 4; ++pt) {
        int gp = pblk * 64 + pt * 16 + n;
        if (gp < PP) {
            bool ex = (excl[gp] != 0);
#pragma unroll
            for (int r = 0; r < 4; ++r) {
                float sv = ex ? NEGINF : acc[pt][r];
                if (sv > bs[r]) { bs[r] = sv; bi[r] = gp; }   // pt ascending -> lowest gp on tie
            }
        }
    }
    // reduce over the 16 lanes of this quad-row group (xor 1,2,4,8 stays in group)
#pragma unroll
    for (int off = 1; off <= 8; off <<= 1) {
#pragma unroll
        for (int r = 0; r < 4; ++r) {
            float s2 = __shfl_xor(bs[r], off, 64);
            int   i2 = __shfl_xor(bi[r], off, 64);
            if (s2 > bs[r] || (s2 == bs[r] && i2 < bi[r])) { bs[r] = s2; bi[r] = i2; }
        }
    }
    if (n == 0) {
#pragma unroll
        for (int r = 0; r < 4; ++r) {
            int slot = qtile * 16 + quad * 4 + r;
            pscore[slot * NTILE + pblk] = bs[r];
            pidx[slot * NTILE + pblk] = bi[r];
        }
    }
}

// ---------------- reduce partials -> best[q]: one block (64 thr) per slot ----------------
__global__ __launch_bounds__(64) void k_reduce(const float* __restrict__ pscore,
                                               const int* __restrict__ pidx,
                                               const int* __restrict__ qlist,
                                               const int* __restrict__ nvalid,
                                               int* __restrict__ best) {
    const int slot = blockIdx.x;
    if (slot >= *nvalid) return;
    const int t = threadIdx.x;
    float bs = -3.4e38f;
    int bi = 0x7fffffff;
    for (int k = t; k < NTILE; k += 64) {
        float s = pscore[slot * NTILE + k];
        int i = pidx[slot * NTILE + k];
        if (s > bs || (s == bs && i < bi)) { bs = s; bi = i; }
    }
#pragma unroll
    for (int off = 32; off >= 1; off >>= 1) {
        float s2 = __shfl_down(bs, off);
        int   i2 = __shfl_down(bi, off);
        if (s2 > bs || (s2 == bs && i2 < bi)) { bs = s2; bi = i2; }
    }
    if (t == 0) best[qlist[slot]] = bi;
}

// ---------------- prep: per-pixel count + source-offset list (c-independent) ----------------
__global__ __launch_bounds__(256) void k_prep(const int* __restrict__ best,
                                              const int* __restrict__ valid,
                                              int* __restrict__ cnt,
                                              int* __restrict__ offlist) {
    int pix = blockIdx.x * 256 + threadIdx.x;
    if (pix >= HW) return;
    int i = pix / WW, j = pix % WW;
    int n = 0;
#pragma unroll
    for (int di = 0; di < 4; ++di) {
        int qi = i - di;
        if (qi < 0 || qi >= HPQ) continue;
#pragma unroll
        for (int dj = 0; dj < 4; ++dj) {
            int qj = j - dj;
            if (qj < 0 || qj >= WPQ) continue;
            int q = qi * WPQ + qj;
            if (valid[q]) {
                int b = best[q];
                int bi = b / WPQ, bj = b % WPQ;
                offlist[pix * 16 + n] = (bi + di) * WW + (bj + dj);
                n++;
            }
        }
    }
    cnt[pix] = n;
}

// ---------------- gather + overlap-add + normalize ----------------
__global__ __launch_bounds__(256) void k_out(const float* __restrict__ low,
                                             const int* __restrict__ cnt,
                                             const int* __restrict__ offlist,
                                             float* __restrict__ out) {
    int idx = blockIdx.x * 256 + threadIdx.x;
    if (idx >= CC * HW) return;
    int c = idx / HW;
    int pix = idx % HW;
    int n = cnt[pix];
    if (n > 0) {
        int base = c * HW;
        float acc = 0.f;
        for (int t = 0; t < n; ++t)
            acc += low[base + offlist[pix * 16 + t]];
        out[idx] = acc / ((float)n + 1e-6f);
    } else {
        out[idx] = low[idx];
    }
}

extern "C" void kernel_launch(void* const* d_in, const int* in_sizes, int n_in,
                              void* d_out, int out_size, void* d_ws, size_t ws_size,
                              hipStream_t stream) {
    const float* low  = (const float*)d_in[0];
    const float* high = (const float*)d_in[1];
    const int*   mask = (const int*)d_in[2];
    float* out = (float*)d_out;

    char* ws = (char*)d_ws;
    int*   nvalid = (int*)(ws);                         // 64 B
    int*   qlist  = (int*)(ws + 64);                    // 24,000
    float* invn   = (float*)(ws + 24064);               // 24,064
    int*   excl   = (int*)(ws + 48128);
    int*   valid  = (int*)(ws + 72192);
    int*   best   = (int*)(ws + 96256);
    float* pscore = (float*)(ws + 120320);              // 5952*93*4 = 2,214,144
    int*   pidx   = (int*)(ws + 2334464);               // 2,214,144
    int*   cnt    = (int*)(ws + 4548608);               // 25,600
    int*   offlist= (int*)(ws + 4574208);               // 409,600
    unsigned short* Ahi = (unsigned short*)(ws + 4983808);   // 6,094,848 each
    unsigned short* Alo = (unsigned short*)(ws + 11078656);
    unsigned short* Bhi = (unsigned short*)(ws + 17173504);
    unsigned short* Blo = (unsigned short*)(ws + 23268352);  // end ~29.4 MB

    hipMemsetAsync(nvalid, 0, 4, stream);
    hipLaunchKernelGGL(k_flags, dim3((PP + 63) / 64), dim3(256), 0, stream,
                       low, mask, invn, excl, valid, qlist, nvalid);
    hipLaunchKernelGGL(k_packB, dim3(QTILES * 4), dim3(256), 0, stream,
                       low, invn, Bhi, Blo);
    hipLaunchKernelGGL(k_packA, dim3(QTILES * 4), dim3(256), 0, stream,
                       high, qlist, nvalid, Ahi, Alo);
    hipLaunchKernelGGL(k_score, dim3(NTILE, 93), dim3(256), 0, stream,
                       Ahi, Alo, Bhi, Blo, excl, nvalid, pscore, pidx);
    hipLaunchKernelGGL(k_reduce, dim3(5952), dim3(64), 0, stream,
                       pscore, pidx, qlist, nvalid, best);
    hipLaunchKernelGGL(k_prep, dim3((HW + 255) / 256), dim3(256), 0, stream,
                       best, valid, cnt, offlist);
    hipLaunchKernelGGL(k_out, dim3((CC * HW + 255) / 256), dim3(256), 0, stream,
                       low, cnt, offlist, out);
}